// Round 2
// baseline (269.871 us; speedup 1.0000x reference)
//
#include <hip/hip_runtime.h>

typedef __attribute__((ext_vector_type(4))) float     floatx4;
typedef __attribute__((ext_vector_type(8))) _Float16  f16x8;
typedef __attribute__((ext_vector_type(4))) _Float16  f16x4;

#define NB    4096      // triple batch size
#define DIM   128
#define SLEN  10
#define CN0   20000
#define CN1   2000
#define CN2   15000
#define T1PAD 2048      // padded type-1 table size
#define GMT   16        // nodes per block in rnn kernel
#define HSTR  136       // LDS f16 row stride for h exchange: 16B-aligned, bank-staggered

// ---------------- ws layout (bytes) ----------------
// he0 | he1 | he2 | hwih | hwhh | agg0 | agg1 | tbl1
static constexpr size_t OFF_HE0  = 0;
static constexpr size_t SZ_HE0   = (size_t)CN0 * DIM * 2;
static constexpr size_t OFF_HE1  = OFF_HE0 + SZ_HE0;
static constexpr size_t SZ_HE1   = (size_t)CN1 * DIM * 2;
static constexpr size_t OFF_HE2  = OFF_HE1 + SZ_HE1;
static constexpr size_t SZ_HE2   = (size_t)CN2 * DIM * 2;
static constexpr size_t OFF_WIH  = OFF_HE2 + SZ_HE2;
static constexpr size_t SZ_W     = (size_t)2 * 3 * DIM * DIM * 2;
static constexpr size_t OFF_WHH  = OFF_WIH + SZ_W;
static constexpr size_t OFF_AGG0 = OFF_WHH + SZ_W;
static constexpr size_t SZ_AGG0  = (size_t)6 * NB * DIM * 4;
static constexpr size_t OFF_AGG1 = OFF_AGG0 + SZ_AGG0;
static constexpr size_t SZ_AGG1  = (size_t)6 * T1PAD * DIM * 4;
static constexpr size_t OFF_TBL1 = OFF_AGG1 + SZ_AGG1;

__device__ __forceinline__ float fast_tanh(float x) {
    // 1 - 2/(e^{2x}+1): saturates cleanly at +/-inf (rcp(inf)=0, rcp(1)=1)
    float e = __expf(2.0f * x);
    return 1.0f - 2.0f * __builtin_amdgcn_rcpf(e + 1.0f);
}

// Raw LDS-only barrier: waits LDS ops (cross-wave h exchange) but leaves the
// global x prefetch in flight across the barrier. __syncthreads() would emit
// s_waitcnt vmcnt(0) before s_barrier and drain the prefetch every step.
// The asm memory clobbers sandwich s_barrier so the compiler can neither sink
// the pre-barrier ds_write below it nor hoist the post-barrier ds_read above
// it (llvm.amdgcn.s.barrier alone is not a compiler memory fence).
__device__ __forceinline__ void lds_barrier() {
    asm volatile("s_waitcnt lgkmcnt(0)" ::: "memory");
    __builtin_amdgcn_s_barrier();
    asm volatile("" ::: "memory");
}

// ---------------- prep: fp32 -> fp16 for embeddings + RNN weights ----------------
__global__ __launch_bounds__(256) void prep_kernel(
    const float* __restrict__ e0, const float* __restrict__ e1, const float* __restrict__ e2,
    const float* __restrict__ wih, const float* __restrict__ whh,
    _Float16* __restrict__ h0, _Float16* __restrict__ h1, _Float16* __restrict__ h2,
    _Float16* __restrict__ hwih, _Float16* __restrict__ hwhh)
{
    int i = blockIdx.x * 256 + threadIdx.x;   // in float4 units
    const int n0 = CN0 * DIM / 4, n1 = CN1 * DIM / 4, n2 = CN2 * DIM / 4;
    const int nw = 2 * 3 * DIM * DIM / 4;
    const float* src; _Float16* dst;
    if (i < n0)              { src = e0;  dst = h0;   }
    else if ((i -= n0) < n1) { src = e1;  dst = h1;   }
    else if ((i -= n1) < n2) { src = e2;  dst = h2;   }
    else if ((i -= n2) < nw) { src = wih; dst = hwih; }
    else if ((i -= nw) < nw) { src = whh; dst = hwhh; }
    else return;
    floatx4 v = ((const floatx4*)src)[i];
    f16x4 o = { (_Float16)v[0], (_Float16)v[1], (_Float16)v[2], (_Float16)v[3] };
    ((f16x4*)dst)[i] = o;
}

// ---------------- RNN-mean aggregation: 4 col-split waves ----------------
// r13 structure (resubmitted r14 — round-1 bench died to container flake):
// occupancy attack on the latency-bound per-step barrier loop.
//  * sX LDS staging DELETED. x fragments for step s+1 are prefetched one step
//    ahead straight from global into registers (identical per-lane addressing
//    to the proven step-0 load: emb + nid*DIM + ks*32 + quad*8). x data is
//    read-once, barrier-independent, and L2/LLC-resident (9.5 MB fp16 tables,
//    FETCH_SIZE showed HBM sees ~none of it) — LDS staging bought nothing but
//    a 39 KB footprint. 4 waves load the same 16 rows -> L1 absorbs the 4x.
//  * LDS 48640 -> ~9.4 KB (sNid + sH only). With VGPR<=102 via
//    __launch_bounds__(256,5) -> 5 blocks/CU = 20 waves (was ~2 blocks, 26%).
//    Blocks/CU = independent barrier groups is the controlling variable for
//    hiding the serial h-chain latency (r12 evidence).
//  * In-loop barrier is a raw lgkmcnt(0)+s_barrier (LDS-only drain) so the
//    global prefetch stays in flight across it; __syncthreads would vmcnt(0).
// Block = 256 threads = 4 waves, 16 nodes. Wave w owns cols [32w, 32w+32)
// -> 64-VGPR weight slice (r9-proven resident).
// Transposed-output MFMA: D'[n][node] = sum_k W[n][k] * X[node][k].
__global__ __launch_bounds__(256, 5) void rnn_kernel(
    const int* __restrict__ c_ids,
    const int* __restrict__ nb00, const int* __restrict__ nb01, const int* __restrict__ nb02,
    const int* __restrict__ nb10, const int* __restrict__ nb11, const int* __restrict__ nb12,
    const _Float16* __restrict__ he0, const _Float16* __restrict__ he1, const _Float16* __restrict__ he2,
    const _Float16* __restrict__ hwih, const _Float16* __restrict__ hwhh,
    const float* __restrict__ bih, const float* __restrict__ bhh,
    float* __restrict__ agg0, float* __restrict__ agg1)
{
    const int lnt = blockIdx.y;          // l*3 + nt
    const int nt  = lnt % 3;
    int tile = blockIdx.x;
    int group, nodeBase;
    float* aggOut;
    const int* neighTab;
    if (tile < NB / GMT) {
        group = 0; nodeBase = tile * GMT;
        neighTab = (nt == 0) ? nb00 : (nt == 1) ? nb01 : nb02;
        aggOut = agg0 + (size_t)lnt * NB * DIM;
    } else {
        group = 1; tile -= NB / GMT; nodeBase = tile * GMT;
        neighTab = (nt == 0) ? nb10 : (nt == 1) ? nb11 : nb12;
        aggOut = agg1 + (size_t)lnt * T1PAD * DIM;
    }
    const _Float16* emb = (nt == 0) ? he0 : (nt == 1) ? he1 : he2;

    __shared__ int      sNid[GMT][SLEN];         //  640 B
    __shared__ _Float16 sH[2][GMT * HSTR];       // 8704 B

    const int tid  = threadIdx.x;
    const int wave = tid >> 6;           // 0..3: owns cols [32w, 32w+32)
    const int lane = tid & 63;
    const int quad = lane >> 4;          // 0..3
    const int l16  = lane & 15;

    for (int i = tid; i < GMT * SLEN; i += 256) {
        int n = i / SLEN, s = i - n * SLEN;
        int node = nodeBase + n;
        int id = (group == 0) ? c_ids[node] : min(node, CN1 - 1);
        sNid[n][s] = neighTab[(size_t)id * SLEN + s];
    }
    __syncthreads();

    // Step-0 x straight into registers (per-lane gather)
    f16x8 xb[4];
    {
        int nid0 = sNid[l16][0];
        const _Float16* xr = emb + (size_t)nid0 * DIM;
        #pragma unroll
        for (int ks = 0; ks < 4; ks++)
            xb[ks] = *(const f16x8*)(xr + ks * 32 + quad * 8);
    }

    // This wave's weight slice: rows [wave*32, wave*32+32) of Wih and Whh.
    const _Float16* Wih = hwih + (size_t)lnt * DIM * DIM;
    const _Float16* Whh = hwhh + (size_t)lnt * DIM * DIM;
    f16x8 wihR[2][4], whhR[2][4];        // 64 VGPRs — r9-proven resident
    #pragma unroll
    for (int a = 0; a < 2; a++) {
        int row = wave * 32 + a * 16 + l16;
        #pragma unroll
        for (int ks = 0; ks < 4; ks++) {
            int off = row * DIM + ks * 32 + quad * 8;
            wihR[a][ks] = *(const f16x8*)(Wih + off);
            whhR[a][ks] = *(const f16x8*)(Whh + off);
        }
    }
    floatx4 biasv[2];
    #pragma unroll
    for (int a = 0; a < 2; a++) {
        int n0 = wave * 32 + a * 16 + quad * 4;
        biasv[a] = *(const floatx4*)(bih + lnt * DIM + n0)
                 + *(const floatx4*)(bhh + lnt * DIM + n0);
    }
    floatx4 hsum[2];
    #pragma unroll
    for (int a = 0; a < 2; a++) hsum[a] = (floatx4)0.f;

    // No second barrier needed: only sNid was LDS-staged above, and sH's first
    // read (step 1) is behind the in-loop barrier of step 0.

    for (int s = 0; s < SLEN; s++) {
        // Prefetch next step's x from GLOBAL now (one full step of latency
        // hiding; the raw barrier below leaves these loads in flight).
        // Skipped entirely on the last iteration (no consumer).
        f16x8 xbn[4];
        if (s < SLEN - 1) {
            int nid = sNid[l16][s + 1];
            const _Float16* xr = emb + (size_t)nid * DIM;
            #pragma unroll
            for (int ks = 0; ks < 4; ks++)
                xbn[ks] = *(const f16x8*)(xr + ks * 32 + quad * 8);
        }
        // h_{s-1} B-frags (the only barrier-dependent load)
        f16x8 hb[4];
        if (s > 0) {
            const _Float16* hrow = &sH[(s + 1) & 1][l16 * HSTR];
            #pragma unroll
            for (int ks = 0; ks < 4; ks++)
                hb[ks] = *(const f16x8*)(hrow + ks * 32 + quad * 8);
        }
        floatx4 acc[2];
        #pragma unroll
        for (int a = 0; a < 2; a++) acc[a] = biasv[a];
        #pragma unroll
        for (int ks = 0; ks < 4; ks++)
            #pragma unroll
            for (int a = 0; a < 2; a++)
                acc[a] = __builtin_amdgcn_mfma_f32_16x16x32_f16(wihR[a][ks], xb[ks], acc[a], 0, 0, 0);
        if (s > 0) {
            #pragma unroll
            for (int ks = 0; ks < 4; ks++)
                #pragma unroll
                for (int a = 0; a < 2; a++)
                    acc[a] = __builtin_amdgcn_mfma_f32_16x16x32_f16(whhR[a][ks], hb[ks], acc[a], 0, 0, 0);
        }
        #pragma unroll
        for (int a = 0; a < 2; a++) {
            float h0 = fast_tanh(acc[a][0]);
            float h1 = fast_tanh(acc[a][1]);
            float h2 = fast_tanh(acc[a][2]);
            float h3 = fast_tanh(acc[a][3]);
            hsum[a] += (floatx4){h0, h1, h2, h3};
            f16x4 hq = { (_Float16)h0, (_Float16)h1, (_Float16)h2, (_Float16)h3 };
            int n0 = wave * 32 + a * 16 + quad * 4;
            *(f16x4*)(&sH[s & 1][l16 * HSTR + n0]) = hq;   // ds_write_b64, own cols
        }
        if (s < SLEN - 1) {
            lds_barrier();   // LDS-only drain; x prefetch stays in flight
            #pragma unroll
            for (int ks = 0; ks < 4; ks++) xb[ks] = xbn[ks];
        }
    }

    // agg = mean of 10 states
    int node = nodeBase + l16;
    #pragma unroll
    for (int a = 0; a < 2; a++) {
        int n0 = wave * 32 + a * 16 + quad * 4;
        *(floatx4*)(aggOut + (size_t)node * DIM + n0) = hsum[a] * 0.1f;
    }
}

// ---------------- attention combine (per node, one wave) ----------------
__device__ __forceinline__ float wsum64(float v) {
    #pragma unroll
    for (int off = 32; off > 0; off >>= 1) v += __shfl_xor(v, off, 64);
    return v;
}

__global__ __launch_bounds__(256) void att_kernel(
    const int* __restrict__ c_ids,
    const float* __restrict__ emb0, const float* __restrict__ emb1,
    const float* __restrict__ attW,
    const float* __restrict__ agg0, const float* __restrict__ agg1,
    float* __restrict__ outc, float* __restrict__ tbl1)
{
    const int wave = threadIdx.x >> 6, lane = threadIdx.x & 63;
    int gb = blockIdx.x;
    int group, node, Nn, ntype;
    const float* aggB; const float* emb;
    if (gb < NB / 4) { group = 0; node = gb * 4 + wave; ntype = 0; aggB = agg0; emb = emb0; Nn = NB; }
    else { group = 1; node = (gb - NB / 4) * 4 + wave; ntype = 1; aggB = agg1; emb = emb1; Nn = T1PAD; }
    int id = (group == 0) ? c_ids[node] : min(node, CN1 - 1);
    int d = lane * 2;
    float2 cur = *(const float2*)(emb + (size_t)id * DIM + d);

    #pragma unroll
    for (int l = 0; l < 2; l++) {
        float2 stk[3];
        #pragma unroll
        for (int k = 0; k < 3; k++)
            stk[k] = *(const float2*)(aggB + ((size_t)(l * 3 + k) * Nn + node) * DIM + d);
        const float* aw = attW + (l * 3 + ntype) * 2 * DIM;
        float2 ac = *(const float2*)(aw + d);
        float2 as = *(const float2*)(aw + DIM + d);
        float pc = ac.x * cur.x + ac.y * cur.y;
        float p0 = as.x * cur.x + as.y * cur.y;
        float p1 = as.x * stk[0].x + as.y * stk[0].y;
        float p2 = as.x * stk[1].x + as.y * stk[1].y;
        float p3 = as.x * stk[2].x + as.y * stk[2].y;
        float base = wsum64(pc);
        float s0 = base + wsum64(p0);
        float s1 = base + wsum64(p1);
        float s2 = base + wsum64(p2);
        float s3 = base + wsum64(p3);
        float mx = fmaxf(fmaxf(s0, s1), fmaxf(s2, s3));
        float e0 = __expf(s0 - mx), e1 = __expf(s1 - mx);
        float e2 = __expf(s2 - mx), e3 = __expf(s3 - mx);
        float rs = __builtin_amdgcn_rcpf(e0 + e1 + e2 + e3);
        float w0 = e0 * rs, w1 = e1 * rs, w2 = e2 * rs, w3 = e3 * rs;
        float nx = w0 * cur.x + w1 * stk[0].x + w2 * stk[1].x + w3 * stk[2].x;
        float ny = w0 * cur.y + w1 * stk[0].y + w2 * stk[1].y + w3 * stk[2].y;
        cur.x = nx > 0.f ? nx : 0.01f * nx;
        cur.y = ny > 0.f ? ny : 0.01f * ny;
    }
    float* dst = (group == 0) ? (outc + (size_t)node * DIM + d) : (tbl1 + (size_t)node * DIM + d);
    *(float2*)dst = cur;
}

// ---------------- gather pos/neg outputs from type-1 table ----------------
__global__ __launch_bounds__(256) void gather_kernel(
    const int* __restrict__ pos_ids, const int* __restrict__ neg_ids,
    const float* __restrict__ tbl1, float* __restrict__ outp, float* __restrict__ outn)
{
    int i = blockIdx.x * 256 + threadIdx.x;   // over 2 * NB * 32 float4s
    const int half = NB * 32;
    const int* ids; float* dst; int j = i;
    if (i < half) { ids = pos_ids; dst = outp; }
    else          { ids = neg_ids; dst = outn; j -= half; }
    int b = j >> 5, c = j & 31;
    int id = ids[b];
    ((floatx4*)dst)[j] = ((const floatx4*)tbl1)[(size_t)id * 32 + c];
}

extern "C" void kernel_launch(void* const* d_in, const int* in_sizes, int n_in,
                              void* d_out, int out_size, void* d_ws, size_t ws_size,
                              hipStream_t stream)
{
    const int* c_ids   = (const int*)d_in[0];
    const int* pos_ids = (const int*)d_in[1];
    const int* neg_ids = (const int*)d_in[2];
    const int* nb00 = (const int*)d_in[3];
    const int* nb01 = (const int*)d_in[4];
    const int* nb02 = (const int*)d_in[5];
    const int* nb10 = (const int*)d_in[6];
    const int* nb11 = (const int*)d_in[7];
    const int* nb12 = (const int*)d_in[8];
    const float* emb0 = (const float*)d_in[12];
    const float* emb1 = (const float*)d_in[13];
    const float* emb2 = (const float*)d_in[14];
    const float* rWih = (const float*)d_in[15];
    const float* rWhh = (const float*)d_in[16];
    const float* rbih = (const float*)d_in[17];
    const float* rbhh = (const float*)d_in[18];
    const float* attW = (const float*)d_in[19];

    char* ws = (char*)d_ws;
    _Float16* he0  = (_Float16*)(ws + OFF_HE0);
    _Float16* he1  = (_Float16*)(ws + OFF_HE1);
    _Float16* he2  = (_Float16*)(ws + OFF_HE2);
    _Float16* hwih = (_Float16*)(ws + OFF_WIH);
    _Float16* hwhh = (_Float16*)(ws + OFF_WHH);
    float*    agg0 = (float*)(ws + OFF_AGG0);
    float*    agg1 = (float*)(ws + OFF_AGG1);
    float*    tbl1 = (float*)(ws + OFF_TBL1);

    float* out  = (float*)d_out;
    float* outc = out;
    float* outp = out + (size_t)NB * DIM;
    float* outn = out + (size_t)2 * NB * DIM;

    // 1) fp16 conversion of embeddings + weights
    {
        int total4 = (CN0 + CN1 + CN2) * DIM / 4 + 2 * (2 * 3 * DIM * DIM / 4);
        int blocks = (total4 + 255) / 256;
        prep_kernel<<<blocks, 256, 0, stream>>>(emb0, emb1, emb2, rWih, rWhh,
                                                he0, he1, he2, hwih, hwhh);
    }
    // 2) RNN-mean aggregations: c batch (4096 nodes) + full type-1 table (2048)
    {
        dim3 grid(NB / GMT + T1PAD / GMT, 6);
        rnn_kernel<<<grid, 256, 0, stream>>>(c_ids, nb00, nb01, nb02, nb10, nb11, nb12,
                                             he0, he1, he2, hwih, hwhh, rbih, rbhh,
                                             agg0, agg1);
    }
    // 3) attention combine
    {
        int blocks = NB / 4 + T1PAD / 4;
        att_kernel<<<blocks, 256, 0, stream>>>(c_ids, emb0, emb1, attW, agg0, agg1,
                                               outc, tbl1);
    }
    // 4) gather pos/neg outputs
    {
        int blocks = 2 * NB * 32 / 256;
        gather_kernel<<<blocks, 256, 0, stream>>>(pos_ids, neg_ids, tbl1, outp, outn);
    }
}

// Round 3
// 204.463 us; speedup vs baseline: 1.3199x; 1.3199x over previous
//
#include <hip/hip_runtime.h>

typedef __attribute__((ext_vector_type(4))) float     floatx4;
typedef __attribute__((ext_vector_type(8))) _Float16  f16x8;
typedef __attribute__((ext_vector_type(4))) _Float16  f16x4;

#define NB    4096      // triple batch size
#define DIM   128
#define SLEN  10
#define CN0   20000
#define CN1   2000
#define CN2   15000
#define T1PAD 2048      // padded type-1 table size
#define GMT   16        // nodes per block in rnn kernel
#define HSTR  136       // LDS f16 row stride for h exchange: 16B-aligned, bank-staggered

// ---------------- ws layout (bytes) ----------------
// he0 | he1 | he2 | hwih | hwhh | agg0 | agg1 | tbl1
static constexpr size_t OFF_HE0  = 0;
static constexpr size_t SZ_HE0   = (size_t)CN0 * DIM * 2;
static constexpr size_t OFF_HE1  = OFF_HE0 + SZ_HE0;
static constexpr size_t SZ_HE1   = (size_t)CN1 * DIM * 2;
static constexpr size_t OFF_HE2  = OFF_HE1 + SZ_HE1;
static constexpr size_t SZ_HE2   = (size_t)CN2 * DIM * 2;
static constexpr size_t OFF_WIH  = OFF_HE2 + SZ_HE2;
static constexpr size_t SZ_W     = (size_t)2 * 3 * DIM * DIM * 2;
static constexpr size_t OFF_WHH  = OFF_WIH + SZ_W;
static constexpr size_t OFF_AGG0 = OFF_WHH + SZ_W;
static constexpr size_t SZ_AGG0  = (size_t)6 * NB * DIM * 4;
static constexpr size_t OFF_AGG1 = OFF_AGG0 + SZ_AGG0;
static constexpr size_t SZ_AGG1  = (size_t)6 * T1PAD * DIM * 4;
static constexpr size_t OFF_TBL1 = OFF_AGG1 + SZ_AGG1;

__device__ __forceinline__ float fast_tanh(float x) {
    // 1 - 2/(e^{2x}+1): saturates cleanly at +/-inf (rcp(inf)=0, rcp(1)=1)
    float e = __expf(2.0f * x);
    return 1.0f - 2.0f * __builtin_amdgcn_rcpf(e + 1.0f);
}

// Raw LDS-only barrier: waits LDS ops (cross-wave h exchange) but leaves the
// global x prefetch in flight across the barrier. __syncthreads() would emit
// s_waitcnt vmcnt(0) before s_barrier and drain the prefetch every step.
// The asm memory clobbers sandwich s_barrier so the compiler can neither sink
// the pre-barrier ds_write below it nor hoist the post-barrier ds_read above
// it (llvm.amdgcn.s.barrier alone is not a compiler memory fence).
__device__ __forceinline__ void lds_barrier() {
    asm volatile("s_waitcnt lgkmcnt(0)" ::: "memory");
    __builtin_amdgcn_s_barrier();
    asm volatile("" ::: "memory");
}

// ---------------- prep: fp32 -> fp16 for embeddings + RNN weights ----------------
__global__ __launch_bounds__(256) void prep_kernel(
    const float* __restrict__ e0, const float* __restrict__ e1, const float* __restrict__ e2,
    const float* __restrict__ wih, const float* __restrict__ whh,
    _Float16* __restrict__ h0, _Float16* __restrict__ h1, _Float16* __restrict__ h2,
    _Float16* __restrict__ hwih, _Float16* __restrict__ hwhh)
{
    int i = blockIdx.x * 256 + threadIdx.x;   // in float4 units
    const int n0 = CN0 * DIM / 4, n1 = CN1 * DIM / 4, n2 = CN2 * DIM / 4;
    const int nw = 2 * 3 * DIM * DIM / 4;
    const float* src; _Float16* dst;
    if (i < n0)              { src = e0;  dst = h0;   }
    else if ((i -= n0) < n1) { src = e1;  dst = h1;   }
    else if ((i -= n1) < n2) { src = e2;  dst = h2;   }
    else if ((i -= n2) < nw) { src = wih; dst = hwih; }
    else if ((i -= nw) < nw) { src = whh; dst = hwhh; }
    else return;
    floatx4 v = ((const floatx4*)src)[i];
    f16x4 o = { (_Float16)v[0], (_Float16)v[1], (_Float16)v[2], (_Float16)v[3] };
    ((f16x4*)dst)[i] = o;
}

// ---------------- RNN-mean aggregation: 4 col-split waves ----------------
// r15 = r14 structure with the launch-bound fix.
// r14 POST-MORTEM: __launch_bounds__(256,5) — 5 is not an achievable
// waves/SIMD step ({1,2,4,8}) — made the compiler cap VGPRs near the 8-wave
// 64-VGPR bin: VGPR_Count 84->48, the 64-VGPR weight slice spilled to
// scratch, WRITE_SIZE 18MB->336MB, FETCH 27MB->305MB, dur 50us->177us.
// Structure itself was proven: passed, occupancy 26%->46%, LDS 9728 B.
// Fix: (256,4) — exact step, VGPR cap 128 >= natural ~84-90, zero spill,
// 4 blocks/CU = 16 waves/CU (~50%), double the r12 baseline's 2 blocks.
//  * sX LDS staging DELETED. x fragments for step s+1 are prefetched one step
//    ahead straight from global into registers (identical per-lane addressing
//    to the proven step-0 load). x data is read-once, barrier-independent,
//    and L2/LLC-resident (9.5 MB fp16 tables) — LDS staging bought nothing
//    but a 39 KB footprint capping occupancy at 2 blocks/CU.
//  * In-loop barrier is a raw lgkmcnt(0)+s_barrier (LDS-only drain) so the
//    global prefetch stays in flight across it; __syncthreads would vmcnt(0).
// Block = 256 threads = 4 waves, 16 nodes. Wave w owns cols [32w, 32w+32)
// -> 64-VGPR weight slice (r9-proven resident).
// Transposed-output MFMA: D'[n][node] = sum_k W[n][k] * X[node][k].
__global__ __launch_bounds__(256, 4) void rnn_kernel(
    const int* __restrict__ c_ids,
    const int* __restrict__ nb00, const int* __restrict__ nb01, const int* __restrict__ nb02,
    const int* __restrict__ nb10, const int* __restrict__ nb11, const int* __restrict__ nb12,
    const _Float16* __restrict__ he0, const _Float16* __restrict__ he1, const _Float16* __restrict__ he2,
    const _Float16* __restrict__ hwih, const _Float16* __restrict__ hwhh,
    const float* __restrict__ bih, const float* __restrict__ bhh,
    float* __restrict__ agg0, float* __restrict__ agg1)
{
    const int lnt = blockIdx.y;          // l*3 + nt
    const int nt  = lnt % 3;
    int tile = blockIdx.x;
    int group, nodeBase;
    float* aggOut;
    const int* neighTab;
    if (tile < NB / GMT) {
        group = 0; nodeBase = tile * GMT;
        neighTab = (nt == 0) ? nb00 : (nt == 1) ? nb01 : nb02;
        aggOut = agg0 + (size_t)lnt * NB * DIM;
    } else {
        group = 1; tile -= NB / GMT; nodeBase = tile * GMT;
        neighTab = (nt == 0) ? nb10 : (nt == 1) ? nb11 : nb12;
        aggOut = agg1 + (size_t)lnt * T1PAD * DIM;
    }
    const _Float16* emb = (nt == 0) ? he0 : (nt == 1) ? he1 : he2;

    __shared__ int      sNid[GMT][SLEN];         //  640 B
    __shared__ _Float16 sH[2][GMT * HSTR];       // 8704 B

    const int tid  = threadIdx.x;
    const int wave = tid >> 6;           // 0..3: owns cols [32w, 32w+32)
    const int lane = tid & 63;
    const int quad = lane >> 4;          // 0..3
    const int l16  = lane & 15;

    for (int i = tid; i < GMT * SLEN; i += 256) {
        int n = i / SLEN, s = i - n * SLEN;
        int node = nodeBase + n;
        int id = (group == 0) ? c_ids[node] : min(node, CN1 - 1);
        sNid[n][s] = neighTab[(size_t)id * SLEN + s];
    }
    __syncthreads();

    // Step-0 x straight into registers (per-lane gather)
    f16x8 xb[4];
    {
        int nid0 = sNid[l16][0];
        const _Float16* xr = emb + (size_t)nid0 * DIM;
        #pragma unroll
        for (int ks = 0; ks < 4; ks++)
            xb[ks] = *(const f16x8*)(xr + ks * 32 + quad * 8);
    }

    // This wave's weight slice: rows [wave*32, wave*32+32) of Wih and Whh.
    const _Float16* Wih = hwih + (size_t)lnt * DIM * DIM;
    const _Float16* Whh = hwhh + (size_t)lnt * DIM * DIM;
    f16x8 wihR[2][4], whhR[2][4];        // 64 VGPRs — r9-proven resident
    #pragma unroll
    for (int a = 0; a < 2; a++) {
        int row = wave * 32 + a * 16 + l16;
        #pragma unroll
        for (int ks = 0; ks < 4; ks++) {
            int off = row * DIM + ks * 32 + quad * 8;
            wihR[a][ks] = *(const f16x8*)(Wih + off);
            whhR[a][ks] = *(const f16x8*)(Whh + off);
        }
    }
    floatx4 biasv[2];
    #pragma unroll
    for (int a = 0; a < 2; a++) {
        int n0 = wave * 32 + a * 16 + quad * 4;
        biasv[a] = *(const floatx4*)(bih + lnt * DIM + n0)
                 + *(const floatx4*)(bhh + lnt * DIM + n0);
    }
    floatx4 hsum[2];
    #pragma unroll
    for (int a = 0; a < 2; a++) hsum[a] = (floatx4)0.f;

    // No second barrier needed: only sNid was LDS-staged above, and sH's first
    // read (step 1) is behind the in-loop barrier of step 0.

    for (int s = 0; s < SLEN; s++) {
        // Prefetch next step's x from GLOBAL now (one full step of latency
        // hiding; the raw barrier below leaves these loads in flight).
        // Skipped entirely on the last iteration (no consumer).
        f16x8 xbn[4];
        if (s < SLEN - 1) {
            int nid = sNid[l16][s + 1];
            const _Float16* xr = emb + (size_t)nid * DIM;
            #pragma unroll
            for (int ks = 0; ks < 4; ks++)
                xbn[ks] = *(const f16x8*)(xr + ks * 32 + quad * 8);
        }
        // h_{s-1} B-frags (the only barrier-dependent load)
        f16x8 hb[4];
        if (s > 0) {
            const _Float16* hrow = &sH[(s + 1) & 1][l16 * HSTR];
            #pragma unroll
            for (int ks = 0; ks < 4; ks++)
                hb[ks] = *(const f16x8*)(hrow + ks * 32 + quad * 8);
        }
        floatx4 acc[2];
        #pragma unroll
        for (int a = 0; a < 2; a++) acc[a] = biasv[a];
        #pragma unroll
        for (int ks = 0; ks < 4; ks++)
            #pragma unroll
            for (int a = 0; a < 2; a++)
                acc[a] = __builtin_amdgcn_mfma_f32_16x16x32_f16(wihR[a][ks], xb[ks], acc[a], 0, 0, 0);
        if (s > 0) {
            #pragma unroll
            for (int ks = 0; ks < 4; ks++)
                #pragma unroll
                for (int a = 0; a < 2; a++)
                    acc[a] = __builtin_amdgcn_mfma_f32_16x16x32_f16(whhR[a][ks], hb[ks], acc[a], 0, 0, 0);
        }
        #pragma unroll
        for (int a = 0; a < 2; a++) {
            float h0 = fast_tanh(acc[a][0]);
            float h1 = fast_tanh(acc[a][1]);
            float h2 = fast_tanh(acc[a][2]);
            float h3 = fast_tanh(acc[a][3]);
            hsum[a] += (floatx4){h0, h1, h2, h3};
            f16x4 hq = { (_Float16)h0, (_Float16)h1, (_Float16)h2, (_Float16)h3 };
            int n0 = wave * 32 + a * 16 + quad * 4;
            *(f16x4*)(&sH[s & 1][l16 * HSTR + n0]) = hq;   // ds_write_b64, own cols
        }
        if (s < SLEN - 1) {
            lds_barrier();   // LDS-only drain; x prefetch stays in flight
            #pragma unroll
            for (int ks = 0; ks < 4; ks++) xb[ks] = xbn[ks];
        }
    }

    // agg = mean of 10 states
    int node = nodeBase + l16;
    #pragma unroll
    for (int a = 0; a < 2; a++) {
        int n0 = wave * 32 + a * 16 + quad * 4;
        *(floatx4*)(aggOut + (size_t)node * DIM + n0) = hsum[a] * 0.1f;
    }
}

// ---------------- attention combine (per node, one wave) ----------------
__device__ __forceinline__ float wsum64(float v) {
    #pragma unroll
    for (int off = 32; off > 0; off >>= 1) v += __shfl_xor(v, off, 64);
    return v;
}

__global__ __launch_bounds__(256) void att_kernel(
    const int* __restrict__ c_ids,
    const float* __restrict__ emb0, const float* __restrict__ emb1,
    const float* __restrict__ attW,
    const float* __restrict__ agg0, const float* __restrict__ agg1,
    float* __restrict__ outc, float* __restrict__ tbl1)
{
    const int wave = threadIdx.x >> 6, lane = threadIdx.x & 63;
    int gb = blockIdx.x;
    int group, node, Nn, ntype;
    const float* aggB; const float* emb;
    if (gb < NB / 4) { group = 0; node = gb * 4 + wave; ntype = 0; aggB = agg0; emb = emb0; Nn = NB; }
    else { group = 1; node = (gb - NB / 4) * 4 + wave; ntype = 1; aggB = agg1; emb = emb1; Nn = T1PAD; }
    int id = (group == 0) ? c_ids[node] : min(node, CN1 - 1);
    int d = lane * 2;
    float2 cur = *(const float2*)(emb + (size_t)id * DIM + d);

    #pragma unroll
    for (int l = 0; l < 2; l++) {
        float2 stk[3];
        #pragma unroll
        for (int k = 0; k < 3; k++)
            stk[k] = *(const float2*)(aggB + ((size_t)(l * 3 + k) * Nn + node) * DIM + d);
        const float* aw = attW + (l * 3 + ntype) * 2 * DIM;
        float2 ac = *(const float2*)(aw + d);
        float2 as = *(const float2*)(aw + DIM + d);
        float pc = ac.x * cur.x + ac.y * cur.y;
        float p0 = as.x * cur.x + as.y * cur.y;
        float p1 = as.x * stk[0].x + as.y * stk[0].y;
        float p2 = as.x * stk[1].x + as.y * stk[1].y;
        float p3 = as.x * stk[2].x + as.y * stk[2].y;
        float base = wsum64(pc);
        float s0 = base + wsum64(p0);
        float s1 = base + wsum64(p1);
        float s2 = base + wsum64(p2);
        float s3 = base + wsum64(p3);
        float mx = fmaxf(fmaxf(s0, s1), fmaxf(s2, s3));
        float e0 = __expf(s0 - mx), e1 = __expf(s1 - mx);
        float e2 = __expf(s2 - mx), e3 = __expf(s3 - mx);
        float rs = __builtin_amdgcn_rcpf(e0 + e1 + e2 + e3);
        float w0 = e0 * rs, w1 = e1 * rs, w2 = e2 * rs, w3 = e3 * rs;
        float nx = w0 * cur.x + w1 * stk[0].x + w2 * stk[1].x + w3 * stk[2].x;
        float ny = w0 * cur.y + w1 * stk[0].y + w2 * stk[1].y + w3 * stk[2].y;
        cur.x = nx > 0.f ? nx : 0.01f * nx;
        cur.y = ny > 0.f ? ny : 0.01f * ny;
    }
    float* dst = (group == 0) ? (outc + (size_t)node * DIM + d) : (tbl1 + (size_t)node * DIM + d);
    *(float2*)dst = cur;
}

// ---------------- gather pos/neg outputs from type-1 table ----------------
__global__ __launch_bounds__(256) void gather_kernel(
    const int* __restrict__ pos_ids, const int* __restrict__ neg_ids,
    const float* __restrict__ tbl1, float* __restrict__ outp, float* __restrict__ outn)
{
    int i = blockIdx.x * 256 + threadIdx.x;   // over 2 * NB * 32 float4s
    const int half = NB * 32;
    const int* ids; float* dst; int j = i;
    if (i < half) { ids = pos_ids; dst = outp; }
    else          { ids = neg_ids; dst = outn; j -= half; }
    int b = j >> 5, c = j & 31;
    int id = ids[b];
    ((floatx4*)dst)[j] = ((const floatx4*)tbl1)[(size_t)id * 32 + c];
}

extern "C" void kernel_launch(void* const* d_in, const int* in_sizes, int n_in,
                              void* d_out, int out_size, void* d_ws, size_t ws_size,
                              hipStream_t stream)
{
    const int* c_ids   = (const int*)d_in[0];
    const int* pos_ids = (const int*)d_in[1];
    const int* neg_ids = (const int*)d_in[2];
    const int* nb00 = (const int*)d_in[3];
    const int* nb01 = (const int*)d_in[4];
    const int* nb02 = (const int*)d_in[5];
    const int* nb10 = (const int*)d_in[6];
    const int* nb11 = (const int*)d_in[7];
    const int* nb12 = (const int*)d_in[8];
    const float* emb0 = (const float*)d_in[12];
    const float* emb1 = (const float*)d_in[13];
    const float* emb2 = (const float*)d_in[14];
    const float* rWih = (const float*)d_in[15];
    const float* rWhh = (const float*)d_in[16];
    const float* rbih = (const float*)d_in[17];
    const float* rbhh = (const float*)d_in[18];
    const float* attW = (const float*)d_in[19];

    char* ws = (char*)d_ws;
    _Float16* he0  = (_Float16*)(ws + OFF_HE0);
    _Float16* he1  = (_Float16*)(ws + OFF_HE1);
    _Float16* he2  = (_Float16*)(ws + OFF_HE2);
    _Float16* hwih = (_Float16*)(ws + OFF_WIH);
    _Float16* hwhh = (_Float16*)(ws + OFF_WHH);
    float*    agg0 = (float*)(ws + OFF_AGG0);
    float*    agg1 = (float*)(ws + OFF_AGG1);
    float*    tbl1 = (float*)(ws + OFF_TBL1);

    float* out  = (float*)d_out;
    float* outc = out;
    float* outp = out + (size_t)NB * DIM;
    float* outn = out + (size_t)2 * NB * DIM;

    // 1) fp16 conversion of embeddings + weights
    {
        int total4 = (CN0 + CN1 + CN2) * DIM / 4 + 2 * (2 * 3 * DIM * DIM / 4);
        int blocks = (total4 + 255) / 256;
        prep_kernel<<<blocks, 256, 0, stream>>>(emb0, emb1, emb2, rWih, rWhh,
                                                he0, he1, he2, hwih, hwhh);
    }
    // 2) RNN-mean aggregations: c batch (4096 nodes) + full type-1 table (2048)
    {
        dim3 grid(NB / GMT + T1PAD / GMT, 6);
        rnn_kernel<<<grid, 256, 0, stream>>>(c_ids, nb00, nb01, nb02, nb10, nb11, nb12,
                                             he0, he1, he2, hwih, hwhh, rbih, rbhh,
                                             agg0, agg1);
    }
    // 3) attention combine
    {
        int blocks = NB / 4 + T1PAD / 4;
        att_kernel<<<blocks, 256, 0, stream>>>(c_ids, emb0, emb1, attW, agg0, agg1,
                                               outc, tbl1);
    }
    // 4) gather pos/neg outputs
    {
        int blocks = 2 * NB * 32 / 256;
        gather_kernel<<<blocks, 256, 0, stream>>>(pos_ids, neg_ids, tbl1, outp, outn);
    }
}

// Round 4
// 190.966 us; speedup vs baseline: 1.4132x; 1.0707x over previous
//
#include <hip/hip_runtime.h>

typedef __attribute__((ext_vector_type(4))) float     floatx4;
typedef __attribute__((ext_vector_type(8))) _Float16  f16x8;
typedef __attribute__((ext_vector_type(4))) _Float16  f16x4;

#define NB    4096      // triple batch size
#define DIM   128
#define SLEN  10
#define CN0   20000
#define CN1   2000
#define CN2   15000
#define T1PAD 2048      // padded type-1 table size
#define GMT   16        // nodes per block in rnn kernel
#define HSTR  136       // LDS f16 row stride for h exchange: 16B-aligned, bank-staggered

// ---------------- ws layout (bytes) ----------------
// he0 | he1 | he2 | hwih | hwhh | agg0 | agg1 | tbl1
static constexpr size_t OFF_HE0  = 0;
static constexpr size_t SZ_HE0   = (size_t)CN0 * DIM * 2;
static constexpr size_t OFF_HE1  = OFF_HE0 + SZ_HE0;
static constexpr size_t SZ_HE1   = (size_t)CN1 * DIM * 2;
static constexpr size_t OFF_HE2  = OFF_HE1 + SZ_HE1;
static constexpr size_t SZ_HE2   = (size_t)CN2 * DIM * 2;
static constexpr size_t OFF_WIH  = OFF_HE2 + SZ_HE2;
static constexpr size_t SZ_W     = (size_t)2 * 3 * DIM * DIM * 2;
static constexpr size_t OFF_WHH  = OFF_WIH + SZ_W;
static constexpr size_t OFF_AGG0 = OFF_WHH + SZ_W;
static constexpr size_t SZ_AGG0  = (size_t)6 * NB * DIM * 4;
static constexpr size_t OFF_AGG1 = OFF_AGG0 + SZ_AGG0;
static constexpr size_t SZ_AGG1  = (size_t)6 * T1PAD * DIM * 4;
static constexpr size_t OFF_TBL1 = OFF_AGG1 + SZ_AGG1;

__device__ __forceinline__ float fast_tanh(float x) {
    // 1 - 2/(e^{2x}+1): saturates cleanly at +/-inf (rcp(inf)=0, rcp(1)=1)
    float e = __expf(2.0f * x);
    return 1.0f - 2.0f * __builtin_amdgcn_rcpf(e + 1.0f);
}

// Raw LDS-only barrier: waits LDS ops (cross-wave h exchange) but leaves the
// global x prefetch in flight across the barrier. __syncthreads() would emit
// s_waitcnt vmcnt(0) before s_barrier and drain the prefetch every step.
// The asm memory clobbers sandwich s_barrier so the compiler can neither sink
// the pre-barrier ds_write below it nor hoist the post-barrier ds_read above
// it (llvm.amdgcn.s.barrier alone is not a compiler memory fence).
__device__ __forceinline__ void lds_barrier() {
    asm volatile("s_waitcnt lgkmcnt(0)" ::: "memory");
    __builtin_amdgcn_s_barrier();
    asm volatile("" ::: "memory");
}

// ---------------- prep: fp32 -> fp16 for embeddings + RNN weights ----------------
__global__ __launch_bounds__(256) void prep_kernel(
    const float* __restrict__ e0, const float* __restrict__ e1, const float* __restrict__ e2,
    const float* __restrict__ wih, const float* __restrict__ whh,
    _Float16* __restrict__ h0, _Float16* __restrict__ h1, _Float16* __restrict__ h2,
    _Float16* __restrict__ hwih, _Float16* __restrict__ hwhh)
{
    int i = blockIdx.x * 256 + threadIdx.x;   // in float4 units
    const int n0 = CN0 * DIM / 4, n1 = CN1 * DIM / 4, n2 = CN2 * DIM / 4;
    const int nw = 2 * 3 * DIM * DIM / 4;
    const float* src; _Float16* dst;
    if (i < n0)              { src = e0;  dst = h0;   }
    else if ((i -= n0) < n1) { src = e1;  dst = h1;   }
    else if ((i -= n1) < n2) { src = e2;  dst = h2;   }
    else if ((i -= n2) < nw) { src = wih; dst = hwih; }
    else if ((i -= nw) < nw) { src = whh; dst = hwhh; }
    else return;
    floatx4 v = ((const floatx4*)src)[i];
    f16x4 o = { (_Float16)v[0], (_Float16)v[1], (_Float16)v[2], (_Float16)v[3] };
    ((f16x4*)dst)[i] = o;
}

// ---------------- RNN-mean aggregation: 4 col-split waves ----------------
// r16 = r15 structure, launch bound reverted to (256,2).
// LAUNCH-BOUNDS POST-MORTEM (r14/r15): hipcc's empirical VGPR cap for
// 256-thread blocks is ~256/arg, NOT 512/arg:
//   arg=2 -> cap 128 (r0: 84 used, no spill)
//   arg=4 -> cap  64 (r15: spilled, WRITE 110MB, FETCH 82MB)
//   arg=5 -> cap  48 (r14: spilled, WRITE 336MB)
// Runtime occupancy is set by ACTUAL VGPR usage bins (<=64: 8 waves/SIMD,
// <=128: 4, <=256: 2), not by the bound. So (256,2) + natural ~100 VGPR
// lands in the <=128 bin -> 4 blocks/CU = 16 waves/CU (~50%), double the
// r0 baseline's LDS-capped 2 blocks — with zero spill.
//  * sX LDS staging DELETED (r13): x fragments for step s+1 prefetched one
//    step ahead straight from global into registers. x is read-once,
//    barrier-independent, L2/LLC-resident (9.5 MB fp16 tables). LDS
//    48640 -> 9728 B, removing the 2-blocks/CU LDS cap.
//  * In-loop barrier is a raw lgkmcnt(0)+s_barrier (LDS-only drain) so the
//    global prefetch stays in flight across it; __syncthreads would vmcnt(0).
// Block = 256 threads = 4 waves, 16 nodes. Wave w owns cols [32w, 32w+32)
// -> 64-VGPR weight slice (r9-proven resident).
// Transposed-output MFMA: D'[n][node] = sum_k W[n][k] * X[node][k].
// If this round shows VGPR >128 or any spill: next step is the 8-wave/block
// restructure (16-row weight slices, ~106 VGPR demand), not more bound tweaks.
__global__ __launch_bounds__(256, 2) void rnn_kernel(
    const int* __restrict__ c_ids,
    const int* __restrict__ nb00, const int* __restrict__ nb01, const int* __restrict__ nb02,
    const int* __restrict__ nb10, const int* __restrict__ nb11, const int* __restrict__ nb12,
    const _Float16* __restrict__ he0, const _Float16* __restrict__ he1, const _Float16* __restrict__ he2,
    const _Float16* __restrict__ hwih, const _Float16* __restrict__ hwhh,
    const float* __restrict__ bih, const float* __restrict__ bhh,
    float* __restrict__ agg0, float* __restrict__ agg1)
{
    const int lnt = blockIdx.y;          // l*3 + nt
    const int nt  = lnt % 3;
    int tile = blockIdx.x;
    int group, nodeBase;
    float* aggOut;
    const int* neighTab;
    if (tile < NB / GMT) {
        group = 0; nodeBase = tile * GMT;
        neighTab = (nt == 0) ? nb00 : (nt == 1) ? nb01 : nb02;
        aggOut = agg0 + (size_t)lnt * NB * DIM;
    } else {
        group = 1; tile -= NB / GMT; nodeBase = tile * GMT;
        neighTab = (nt == 0) ? nb10 : (nt == 1) ? nb11 : nb12;
        aggOut = agg1 + (size_t)lnt * T1PAD * DIM;
    }
    const _Float16* emb = (nt == 0) ? he0 : (nt == 1) ? he1 : he2;

    __shared__ int      sNid[GMT][SLEN];         //  640 B
    __shared__ _Float16 sH[2][GMT * HSTR];       // 8704 B

    const int tid  = threadIdx.x;
    const int wave = tid >> 6;           // 0..3: owns cols [32w, 32w+32)
    const int lane = tid & 63;
    const int quad = lane >> 4;          // 0..3
    const int l16  = lane & 15;

    for (int i = tid; i < GMT * SLEN; i += 256) {
        int n = i / SLEN, s = i - n * SLEN;
        int node = nodeBase + n;
        int id = (group == 0) ? c_ids[node] : min(node, CN1 - 1);
        sNid[n][s] = neighTab[(size_t)id * SLEN + s];
    }
    __syncthreads();

    // Step-0 x straight into registers (per-lane gather)
    f16x8 xb[4];
    {
        int nid0 = sNid[l16][0];
        const _Float16* xr = emb + (size_t)nid0 * DIM;
        #pragma unroll
        for (int ks = 0; ks < 4; ks++)
            xb[ks] = *(const f16x8*)(xr + ks * 32 + quad * 8);
    }

    // This wave's weight slice: rows [wave*32, wave*32+32) of Wih and Whh.
    const _Float16* Wih = hwih + (size_t)lnt * DIM * DIM;
    const _Float16* Whh = hwhh + (size_t)lnt * DIM * DIM;
    f16x8 wihR[2][4], whhR[2][4];        // 64 VGPRs — r9-proven resident
    #pragma unroll
    for (int a = 0; a < 2; a++) {
        int row = wave * 32 + a * 16 + l16;
        #pragma unroll
        for (int ks = 0; ks < 4; ks++) {
            int off = row * DIM + ks * 32 + quad * 8;
            wihR[a][ks] = *(const f16x8*)(Wih + off);
            whhR[a][ks] = *(const f16x8*)(Whh + off);
        }
    }
    floatx4 biasv[2];
    #pragma unroll
    for (int a = 0; a < 2; a++) {
        int n0 = wave * 32 + a * 16 + quad * 4;
        biasv[a] = *(const floatx4*)(bih + lnt * DIM + n0)
                 + *(const floatx4*)(bhh + lnt * DIM + n0);
    }
    floatx4 hsum[2];
    #pragma unroll
    for (int a = 0; a < 2; a++) hsum[a] = (floatx4)0.f;

    // No second barrier needed: only sNid was LDS-staged above, and sH's first
    // read (step 1) is behind the in-loop barrier of step 0.

    for (int s = 0; s < SLEN; s++) {
        // Prefetch next step's x from GLOBAL now (one full step of latency
        // hiding; the raw barrier below leaves these loads in flight).
        // Skipped entirely on the last iteration (no consumer).
        f16x8 xbn[4];
        if (s < SLEN - 1) {
            int nid = sNid[l16][s + 1];
            const _Float16* xr = emb + (size_t)nid * DIM;
            #pragma unroll
            for (int ks = 0; ks < 4; ks++)
                xbn[ks] = *(const f16x8*)(xr + ks * 32 + quad * 8);
        }
        // h_{s-1} B-frags (the only barrier-dependent load)
        f16x8 hb[4];
        if (s > 0) {
            const _Float16* hrow = &sH[(s + 1) & 1][l16 * HSTR];
            #pragma unroll
            for (int ks = 0; ks < 4; ks++)
                hb[ks] = *(const f16x8*)(hrow + ks * 32 + quad * 8);
        }
        floatx4 acc[2];
        #pragma unroll
        for (int a = 0; a < 2; a++) acc[a] = biasv[a];
        #pragma unroll
        for (int ks = 0; ks < 4; ks++)
            #pragma unroll
            for (int a = 0; a < 2; a++)
                acc[a] = __builtin_amdgcn_mfma_f32_16x16x32_f16(wihR[a][ks], xb[ks], acc[a], 0, 0, 0);
        if (s > 0) {
            #pragma unroll
            for (int ks = 0; ks < 4; ks++)
                #pragma unroll
                for (int a = 0; a < 2; a++)
                    acc[a] = __builtin_amdgcn_mfma_f32_16x16x32_f16(whhR[a][ks], hb[ks], acc[a], 0, 0, 0);
        }
        #pragma unroll
        for (int a = 0; a < 2; a++) {
            float h0 = fast_tanh(acc[a][0]);
            float h1 = fast_tanh(acc[a][1]);
            float h2 = fast_tanh(acc[a][2]);
            float h3 = fast_tanh(acc[a][3]);
            hsum[a] += (floatx4){h0, h1, h2, h3};
            f16x4 hq = { (_Float16)h0, (_Float16)h1, (_Float16)h2, (_Float16)h3 };
            int n0 = wave * 32 + a * 16 + quad * 4;
            *(f16x4*)(&sH[s & 1][l16 * HSTR + n0]) = hq;   // ds_write_b64, own cols
        }
        if (s < SLEN - 1) {
            lds_barrier();   // LDS-only drain; x prefetch stays in flight
            #pragma unroll
            for (int ks = 0; ks < 4; ks++) xb[ks] = xbn[ks];
        }
    }

    // agg = mean of 10 states
    int node = nodeBase + l16;
    #pragma unroll
    for (int a = 0; a < 2; a++) {
        int n0 = wave * 32 + a * 16 + quad * 4;
        *(floatx4*)(aggOut + (size_t)node * DIM + n0) = hsum[a] * 0.1f;
    }
}

// ---------------- attention combine (per node, one wave) ----------------
__device__ __forceinline__ float wsum64(float v) {
    #pragma unroll
    for (int off = 32; off > 0; off >>= 1) v += __shfl_xor(v, off, 64);
    return v;
}

__global__ __launch_bounds__(256) void att_kernel(
    const int* __restrict__ c_ids,
    const float* __restrict__ emb0, const float* __restrict__ emb1,
    const float* __restrict__ attW,
    const float* __restrict__ agg0, const float* __restrict__ agg1,
    float* __restrict__ outc, float* __restrict__ tbl1)
{
    const int wave = threadIdx.x >> 6, lane = threadIdx.x & 63;
    int gb = blockIdx.x;
    int group, node, Nn, ntype;
    const float* aggB; const float* emb;
    if (gb < NB / 4) { group = 0; node = gb * 4 + wave; ntype = 0; aggB = agg0; emb = emb0; Nn = NB; }
    else { group = 1; node = (gb - NB / 4) * 4 + wave; ntype = 1; aggB = agg1; emb = emb1; Nn = T1PAD; }
    int id = (group == 0) ? c_ids[node] : min(node, CN1 - 1);
    int d = lane * 2;
    float2 cur = *(const float2*)(emb + (size_t)id * DIM + d);

    #pragma unroll
    for (int l = 0; l < 2; l++) {
        float2 stk[3];
        #pragma unroll
        for (int k = 0; k < 3; k++)
            stk[k] = *(const float2*)(aggB + ((size_t)(l * 3 + k) * Nn + node) * DIM + d);
        const float* aw = attW + (l * 3 + ntype) * 2 * DIM;
        float2 ac = *(const float2*)(aw + d);
        float2 as = *(const float2*)(aw + DIM + d);
        float pc = ac.x * cur.x + ac.y * cur.y;
        float p0 = as.x * cur.x + as.y * cur.y;
        float p1 = as.x * stk[0].x + as.y * stk[0].y;
        float p2 = as.x * stk[1].x + as.y * stk[1].y;
        float p3 = as.x * stk[2].x + as.y * stk[2].y;
        float base = wsum64(pc);
        float s0 = base + wsum64(p0);
        float s1 = base + wsum64(p1);
        float s2 = base + wsum64(p2);
        float s3 = base + wsum64(p3);
        float mx = fmaxf(fmaxf(s0, s1), fmaxf(s2, s3));
        float e0 = __expf(s0 - mx), e1 = __expf(s1 - mx);
        float e2 = __expf(s2 - mx), e3 = __expf(s3 - mx);
        float rs = __builtin_amdgcn_rcpf(e0 + e1 + e2 + e3);
        float w0 = e0 * rs, w1 = e1 * rs, w2 = e2 * rs, w3 = e3 * rs;
        float nx = w0 * cur.x + w1 * stk[0].x + w2 * stk[1].x + w3 * stk[2].x;
        float ny = w0 * cur.y + w1 * stk[0].y + w2 * stk[1].y + w3 * stk[2].y;
        cur.x = nx > 0.f ? nx : 0.01f * nx;
        cur.y = ny > 0.f ? ny : 0.01f * ny;
    }
    float* dst = (group == 0) ? (outc + (size_t)node * DIM + d) : (tbl1 + (size_t)node * DIM + d);
    *(float2*)dst = cur;
}

// ---------------- gather pos/neg outputs from type-1 table ----------------
__global__ __launch_bounds__(256) void gather_kernel(
    const int* __restrict__ pos_ids, const int* __restrict__ neg_ids,
    const float* __restrict__ tbl1, float* __restrict__ outp, float* __restrict__ outn)
{
    int i = blockIdx.x * 256 + threadIdx.x;   // over 2 * NB * 32 float4s
    const int half = NB * 32;
    const int* ids; float* dst; int j = i;
    if (i < half) { ids = pos_ids; dst = outp; }
    else          { ids = neg_ids; dst = outn; j -= half; }
    int b = j >> 5, c = j & 31;
    int id = ids[b];
    ((floatx4*)dst)[j] = ((const floatx4*)tbl1)[(size_t)id * 32 + c];
}

extern "C" void kernel_launch(void* const* d_in, const int* in_sizes, int n_in,
                              void* d_out, int out_size, void* d_ws, size_t ws_size,
                              hipStream_t stream)
{
    const int* c_ids   = (const int*)d_in[0];
    const int* pos_ids = (const int*)d_in[1];
    const int* neg_ids = (const int*)d_in[2];
    const int* nb00 = (const int*)d_in[3];
    const int* nb01 = (const int*)d_in[4];
    const int* nb02 = (const int*)d_in[5];
    const int* nb10 = (const int*)d_in[6];
    const int* nb11 = (const int*)d_in[7];
    const int* nb12 = (const int*)d_in[8];
    const float* emb0 = (const float*)d_in[12];
    const float* emb1 = (const float*)d_in[13];
    const float* emb2 = (const float*)d_in[14];
    const float* rWih = (const float*)d_in[15];
    const float* rWhh = (const float*)d_in[16];
    const float* rbih = (const float*)d_in[17];
    const float* rbhh = (const float*)d_in[18];
    const float* attW = (const float*)d_in[19];

    char* ws = (char*)d_ws;
    _Float16* he0  = (_Float16*)(ws + OFF_HE0);
    _Float16* he1  = (_Float16*)(ws + OFF_HE1);
    _Float16* he2  = (_Float16*)(ws + OFF_HE2);
    _Float16* hwih = (_Float16*)(ws + OFF_WIH);
    _Float16* hwhh = (_Float16*)(ws + OFF_WHH);
    float*    agg0 = (float*)(ws + OFF_AGG0);
    float*    agg1 = (float*)(ws + OFF_AGG1);
    float*    tbl1 = (float*)(ws + OFF_TBL1);

    float* out  = (float*)d_out;
    float* outc = out;
    float* outp = out + (size_t)NB * DIM;
    float* outn = out + (size_t)2 * NB * DIM;

    // 1) fp16 conversion of embeddings + weights
    {
        int total4 = (CN0 + CN1 + CN2) * DIM / 4 + 2 * (2 * 3 * DIM * DIM / 4);
        int blocks = (total4 + 255) / 256;
        prep_kernel<<<blocks, 256, 0, stream>>>(emb0, emb1, emb2, rWih, rWhh,
                                                he0, he1, he2, hwih, hwhh);
    }
    // 2) RNN-mean aggregations: c batch (4096 nodes) + full type-1 table (2048)
    {
        dim3 grid(NB / GMT + T1PAD / GMT, 6);
        rnn_kernel<<<grid, 256, 0, stream>>>(c_ids, nb00, nb01, nb02, nb10, nb11, nb12,
                                             he0, he1, he2, hwih, hwhh, rbih, rbhh,
                                             agg0, agg1);
    }
    // 3) attention combine
    {
        int blocks = NB / 4 + T1PAD / 4;
        att_kernel<<<blocks, 256, 0, stream>>>(c_ids, emb0, emb1, attW, agg0, agg1,
                                               outc, tbl1);
    }
    // 4) gather pos/neg outputs
    {
        int blocks = 2 * NB * 32 / 256;
        gather_kernel<<<blocks, 256, 0, stream>>>(pos_ids, neg_ids, tbl1, outp, outn);
    }
}

// Round 5
// 164.759 us; speedup vs baseline: 1.6380x; 1.1591x over previous
//
#include <hip/hip_runtime.h>

typedef __attribute__((ext_vector_type(4))) float     floatx4;
typedef __attribute__((ext_vector_type(8))) _Float16  f16x8;
typedef __attribute__((ext_vector_type(4))) _Float16  f16x4;

#define NB    4096      // triple batch size
#define DIM   128
#define SLEN  10
#define CN0   20000
#define CN1   2000
#define CN2   15000
#define T1PAD 2048      // padded type-1 table size
#define GMT   16        // nodes per block in rnn kernel
#define XSTR  136       // LDS f16 row stride: 16B-aligned, bank-staggered rows
#define NSLOT 5         // rotating x slots (steps 1..9 share 5 slots mod-5)

// ---------------- ws layout (bytes) ----------------
// he0 | he1 | he2 | hwih | hwhh | agg0 | agg1 | tbl1
static constexpr size_t OFF_HE0  = 0;
static constexpr size_t SZ_HE0   = (size_t)CN0 * DIM * 2;
static constexpr size_t OFF_HE1  = OFF_HE0 + SZ_HE0;
static constexpr size_t SZ_HE1   = (size_t)CN1 * DIM * 2;
static constexpr size_t OFF_HE2  = OFF_HE1 + SZ_HE1;
static constexpr size_t SZ_HE2   = (size_t)CN2 * DIM * 2;
static constexpr size_t OFF_WIH  = OFF_HE2 + SZ_HE2;
static constexpr size_t SZ_W     = (size_t)2 * 3 * DIM * DIM * 2;
static constexpr size_t OFF_WHH  = OFF_WIH + SZ_W;
static constexpr size_t OFF_AGG0 = OFF_WHH + SZ_W;
static constexpr size_t SZ_AGG0  = (size_t)6 * NB * DIM * 4;
static constexpr size_t OFF_AGG1 = OFF_AGG0 + SZ_AGG0;
static constexpr size_t SZ_AGG1  = (size_t)6 * T1PAD * DIM * 4;
static constexpr size_t OFF_TBL1 = OFF_AGG1 + SZ_AGG1;

__device__ __forceinline__ float fast_tanh(float x) {
    // 1 - 2/(e^{2x}+1): saturates cleanly at +/-inf (rcp(inf)=0, rcp(1)=1)
    float e = __expf(2.0f * x);
    return 1.0f - 2.0f * __builtin_amdgcn_rcpf(e + 1.0f);
}

// Raw LDS-only barrier (correctness proven r14-r16): waits LDS ops but leaves
// global loads in flight across the barrier. __syncthreads() would emit
// s_waitcnt vmcnt(0) and drain the pre-loop late-slot loads at every step.
__device__ __forceinline__ void lds_barrier() {
    asm volatile("s_waitcnt lgkmcnt(0)" ::: "memory");
    __builtin_amdgcn_s_barrier();
    asm volatile("" ::: "memory");
}

// ---------------- prep: fp32 -> fp16 for embeddings + RNN weights ----------------
__global__ __launch_bounds__(256) void prep_kernel(
    const float* __restrict__ e0, const float* __restrict__ e1, const float* __restrict__ e2,
    const float* __restrict__ wih, const float* __restrict__ whh,
    _Float16* __restrict__ h0, _Float16* __restrict__ h1, _Float16* __restrict__ h2,
    _Float16* __restrict__ hwih, _Float16* __restrict__ hwhh)
{
    int i = blockIdx.x * 256 + threadIdx.x;   // in float4 units
    const int n0 = CN0 * DIM / 4, n1 = CN1 * DIM / 4, n2 = CN2 * DIM / 4;
    const int nw = 2 * 3 * DIM * DIM / 4;
    const float* src; _Float16* dst;
    if (i < n0)              { src = e0;  dst = h0;   }
    else if ((i -= n0) < n1) { src = e1;  dst = h1;   }
    else if ((i -= n1) < n2) { src = e2;  dst = h2;   }
    else if ((i -= n2) < nw) { src = wih; dst = hwih; }
    else if ((i -= nw) < nw) { src = whh; dst = hwhh; }
    else return;
    floatx4 v = ((const floatx4*)src)[i];
    f16x4 o = { (_Float16)v[0], (_Float16)v[1], (_Float16)v[2], (_Float16)v[3] };
    ((f16x4*)dst)[i] = o;
}

// ---------------- RNN-mean aggregation: 4 col-split waves, 5-slot LDS x ----------------
// r17: keep r0's per-step structure (ALL x reads from LDS — r13-r16 proved
// per-step global gather is 1.6-1.9x slower regardless of occupancy) but cut
// the sX footprint 9 slots -> 5 rotating slots so LDS drops 48640 -> ~31.1KB:
//   * steps 1..5 staged upfront into slots 0..4 (identical to r0 staging).
//   * steps 6..9 loaded global->reg ONCE pre-loop (coalesced, 16B/thread,
//     4 f16x8 held ~4 steps) and ds-written into recycled slots at the tops
//     of steps 2 and 4. Barrier ordering makes the recycling race-free:
//     slot k's last old read is the prefetch at top of step k; the write
//     lands >=1 lds_barrier later; the new read (top of step k+5) is >=3
//     barriers after the write's lgkmcnt(0) drain.
// Occupancy: LDS 31.1KB -> 4 blocks/CU; VGPR ~92+16 stays in the <=128 bin
// (launch_bounds(256,2) — empirical cap 256/arg=128; args 4/5 force 64/48
// and spill, r14/r15). 4 blocks/CU = 2x r0's LDS-capped residency with r0's
// proven per-step latency profile. Downside bounded at ~r0 performance.
// Block = 256 threads = 4 waves, 16 nodes. Wave w owns cols [32w, 32w+32)
// -> 64-VGPR weight slice. Transposed-output MFMA: D'[n][node] = sum_k W[n][k]*X[node][k].
__global__ __launch_bounds__(256, 2) void rnn_kernel(
    const int* __restrict__ c_ids,
    const int* __restrict__ nb00, const int* __restrict__ nb01, const int* __restrict__ nb02,
    const int* __restrict__ nb10, const int* __restrict__ nb11, const int* __restrict__ nb12,
    const _Float16* __restrict__ he0, const _Float16* __restrict__ he1, const _Float16* __restrict__ he2,
    const _Float16* __restrict__ hwih, const _Float16* __restrict__ hwhh,
    const float* __restrict__ bih, const float* __restrict__ bhh,
    float* __restrict__ agg0, float* __restrict__ agg1)
{
    const int lnt = blockIdx.y;          // l*3 + nt
    const int nt  = lnt % 3;
    int tile = blockIdx.x;
    int group, nodeBase;
    float* aggOut;
    const int* neighTab;
    if (tile < NB / GMT) {
        group = 0; nodeBase = tile * GMT;
        neighTab = (nt == 0) ? nb00 : (nt == 1) ? nb01 : nb02;
        aggOut = agg0 + (size_t)lnt * NB * DIM;
    } else {
        group = 1; tile -= NB / GMT; nodeBase = tile * GMT;
        neighTab = (nt == 0) ? nb10 : (nt == 1) ? nb11 : nb12;
        aggOut = agg1 + (size_t)lnt * T1PAD * DIM;
    }
    const _Float16* emb = (nt == 0) ? he0 : (nt == 1) ? he1 : he2;

    __shared__ int      sNid[GMT][SLEN];           //   640 B
    __shared__ _Float16 sX[NSLOT * GMT * XSTR];    // 21760 B (5 rotating slots)
    __shared__ _Float16 sH[2][GMT * XSTR];         //  8704 B

    const int tid  = threadIdx.x;
    const int wave = tid >> 6;           // 0..3: owns cols [32w, 32w+32)
    const int lane = tid & 63;
    const int quad = lane >> 4;          // 0..3
    const int l16  = lane & 15;

    for (int i = tid; i < GMT * SLEN; i += 256) {
        int n = i / SLEN, s = i - n * SLEN;
        int node = nodeBase + n;
        int id = (group == 0) ? c_ids[node] : min(node, CN1 - 1);
        sNid[n][s] = neighTab[(size_t)id * SLEN + s];
    }
    __syncthreads();

    // Step-0 x straight into registers (per-lane gather, overlaps staging)
    f16x8 xb[4];
    {
        int nid0 = sNid[l16][0];
        const _Float16* xr = emb + (size_t)nid0 * DIM;
        #pragma unroll
        for (int ks = 0; ks < 4; ks++)
            xb[ks] = *(const f16x8*)(xr + ks * 32 + quad * 8);
    }

    // Upfront staging: steps 1..5 -> slots 0..4. 80 rows x 16 chunks of 16B,
    // coalesced (16 consecutive threads read one 256B row), 5 tasks/thread.
    for (int i = tid; i < GMT * NSLOT * 16; i += 256) {
        int c  = i & 15;
        int rs = i >> 4;              // 0..79
        int n  = rs & 15, sl = rs >> 4;   // slot sl holds step sl+1
        int nid = sNid[n][sl + 1];
        f16x8 v = *(const f16x8*)(emb + (size_t)nid * DIM + c * 8);
        *(f16x8*)(&sX[(sl * GMT + n) * XSTR + c * 8]) = v;
    }

    // Late-step loads (steps 6..9 -> recycled slots 0..3): issue NOW, hold in
    // 16 VGPRs, ds_write at the tops of steps 2 and 4. Coalesced 16B/thread.
    const int lrow = tid >> 4, lchk = tid & 15;     // row 0..15, chunk 0..15
    f16x8 xl0, xl1, xl2, xl3;
    {
        const size_t co = (size_t)lchk * 8;
        xl0 = *(const f16x8*)(emb + (size_t)sNid[lrow][6] * DIM + co);  // step 6 -> slot 0
        xl1 = *(const f16x8*)(emb + (size_t)sNid[lrow][7] * DIM + co);  // step 7 -> slot 1
        xl2 = *(const f16x8*)(emb + (size_t)sNid[lrow][8] * DIM + co);  // step 8 -> slot 2
        xl3 = *(const f16x8*)(emb + (size_t)sNid[lrow][9] * DIM + co);  // step 9 -> slot 3
    }

    // This wave's weight slice: rows [wave*32, wave*32+32) of Wih and Whh.
    const _Float16* Wih = hwih + (size_t)lnt * DIM * DIM;
    const _Float16* Whh = hwhh + (size_t)lnt * DIM * DIM;
    f16x8 wihR[2][4], whhR[2][4];        // 64 VGPRs — proven resident
    #pragma unroll
    for (int a = 0; a < 2; a++) {
        int row = wave * 32 + a * 16 + l16;
        #pragma unroll
        for (int ks = 0; ks < 4; ks++) {
            int off = row * DIM + ks * 32 + quad * 8;
            wihR[a][ks] = *(const f16x8*)(Wih + off);
            whhR[a][ks] = *(const f16x8*)(Whh + off);
        }
    }
    floatx4 biasv[2];
    #pragma unroll
    for (int a = 0; a < 2; a++) {
        int n0 = wave * 32 + a * 16 + quad * 4;
        biasv[a] = *(const floatx4*)(bih + lnt * DIM + n0)
                 + *(const floatx4*)(bhh + lnt * DIM + n0);
    }
    floatx4 hsum[2];
    #pragma unroll
    for (int a = 0; a < 2; a++) hsum[a] = (floatx4)0.f;

    // sX slots 0..4 visible after this; late loads + weight loads stay in
    // flight (lds_barrier waits lgkmcnt only — their uses force vmcnt waits).
    lds_barrier();

    for (int s = 0; s < SLEN; s++) {
        // h_{s-1} B-frags (the only barrier-dependent load)
        f16x8 hb[4];
        if (s > 0) {
            const _Float16* hrow = &sH[(s + 1) & 1][l16 * XSTR];
            #pragma unroll
            for (int ks = 0; ks < 4; ks++)
                hb[ks] = *(const f16x8*)(hrow + ks * 32 + quad * 8);
        }
        // Prefetch next step's x from its slot (step s+1 -> slot s % 5).
        f16x8 xbn[4];
        if (s < SLEN - 1) {
            const _Float16* xrow = &sX[((s % NSLOT) * GMT + l16) * XSTR];
            #pragma unroll
            for (int ks = 0; ks < 4; ks++)
                xbn[ks] = *(const f16x8*)(xrow + ks * 32 + quad * 8);
        }
        // Slot recycling: write steps 6,7 at top of step 2 (slots 0,1 — last
        // old reads were at tops of steps 0,1, separated by barriers); write
        // steps 8,9 at top of step 4 (slots 2,3 — old reads at steps 2,3).
        if (s == 2) {
            *(f16x8*)(&sX[(0 * GMT + lrow) * XSTR + lchk * 8]) = xl0;
            *(f16x8*)(&sX[(1 * GMT + lrow) * XSTR + lchk * 8]) = xl1;
        }
        if (s == 4) {
            *(f16x8*)(&sX[(2 * GMT + lrow) * XSTR + lchk * 8]) = xl2;
            *(f16x8*)(&sX[(3 * GMT + lrow) * XSTR + lchk * 8]) = xl3;
        }
        floatx4 acc[2];
        #pragma unroll
        for (int a = 0; a < 2; a++) acc[a] = biasv[a];
        #pragma unroll
        for (int ks = 0; ks < 4; ks++)
            #pragma unroll
            for (int a = 0; a < 2; a++)
                acc[a] = __builtin_amdgcn_mfma_f32_16x16x32_f16(wihR[a][ks], xb[ks], acc[a], 0, 0, 0);
        if (s > 0) {
            #pragma unroll
            for (int ks = 0; ks < 4; ks++)
                #pragma unroll
                for (int a = 0; a < 2; a++)
                    acc[a] = __builtin_amdgcn_mfma_f32_16x16x32_f16(whhR[a][ks], hb[ks], acc[a], 0, 0, 0);
        }
        #pragma unroll
        for (int a = 0; a < 2; a++) {
            float h0 = fast_tanh(acc[a][0]);
            float h1 = fast_tanh(acc[a][1]);
            float h2 = fast_tanh(acc[a][2]);
            float h3 = fast_tanh(acc[a][3]);
            hsum[a] += (floatx4){h0, h1, h2, h3};
            f16x4 hq = { (_Float16)h0, (_Float16)h1, (_Float16)h2, (_Float16)h3 };
            int n0 = wave * 32 + a * 16 + quad * 4;
            *(f16x4*)(&sH[s & 1][l16 * XSTR + n0]) = hq;   // ds_write_b64, own cols
        }
        if (s < SLEN - 1) {
            lds_barrier();   // drains LDS (incl. slot recycling); globals fly on
            #pragma unroll
            for (int ks = 0; ks < 4; ks++) xb[ks] = xbn[ks];
        }
    }

    // agg = mean of 10 states
    int node = nodeBase + l16;
    #pragma unroll
    for (int a = 0; a < 2; a++) {
        int n0 = wave * 32 + a * 16 + quad * 4;
        *(floatx4*)(aggOut + (size_t)node * DIM + n0) = hsum[a] * 0.1f;
    }
}

// ---------------- attention combine (per node, one wave) ----------------
__device__ __forceinline__ float wsum64(float v) {
    #pragma unroll
    for (int off = 32; off > 0; off >>= 1) v += __shfl_xor(v, off, 64);
    return v;
}

__global__ __launch_bounds__(256) void att_kernel(
    const int* __restrict__ c_ids,
    const float* __restrict__ emb0, const float* __restrict__ emb1,
    const float* __restrict__ attW,
    const float* __restrict__ agg0, const float* __restrict__ agg1,
    float* __restrict__ outc, float* __restrict__ tbl1)
{
    const int wave = threadIdx.x >> 6, lane = threadIdx.x & 63;
    int gb = blockIdx.x;
    int group, node, Nn, ntype;
    const float* aggB; const float* emb;
    if (gb < NB / 4) { group = 0; node = gb * 4 + wave; ntype = 0; aggB = agg0; emb = emb0; Nn = NB; }
    else { group = 1; node = (gb - NB / 4) * 4 + wave; ntype = 1; aggB = agg1; emb = emb1; Nn = T1PAD; }
    int id = (group == 0) ? c_ids[node] : min(node, CN1 - 1);
    int d = lane * 2;
    float2 cur = *(const float2*)(emb + (size_t)id * DIM + d);

    #pragma unroll
    for (int l = 0; l < 2; l++) {
        float2 stk[3];
        #pragma unroll
        for (int k = 0; k < 3; k++)
            stk[k] = *(const float2*)(aggB + ((size_t)(l * 3 + k) * Nn + node) * DIM + d);
        const float* aw = attW + (l * 3 + ntype) * 2 * DIM;
        float2 ac = *(const float2*)(aw + d);
        float2 as = *(const float2*)(aw + DIM + d);
        float pc = ac.x * cur.x + ac.y * cur.y;
        float p0 = as.x * cur.x + as.y * cur.y;
        float p1 = as.x * stk[0].x + as.y * stk[0].y;
        float p2 = as.x * stk[1].x + as.y * stk[1].y;
        float p3 = as.x * stk[2].x + as.y * stk[2].y;
        float base = wsum64(pc);
        float s0 = base + wsum64(p0);
        float s1 = base + wsum64(p1);
        float s2 = base + wsum64(p2);
        float s3 = base + wsum64(p3);
        float mx = fmaxf(fmaxf(s0, s1), fmaxf(s2, s3));
        float e0 = __expf(s0 - mx), e1 = __expf(s1 - mx);
        float e2 = __expf(s2 - mx), e3 = __expf(s3 - mx);
        float rs = __builtin_amdgcn_rcpf(e0 + e1 + e2 + e3);
        float w0 = e0 * rs, w1 = e1 * rs, w2 = e2 * rs, w3 = e3 * rs;
        float nx = w0 * cur.x + w1 * stk[0].x + w2 * stk[1].x + w3 * stk[2].x;
        float ny = w0 * cur.y + w1 * stk[0].y + w2 * stk[1].y + w3 * stk[2].y;
        cur.x = nx > 0.f ? nx : 0.01f * nx;
        cur.y = ny > 0.f ? ny : 0.01f * ny;
    }
    float* dst = (group == 0) ? (outc + (size_t)node * DIM + d) : (tbl1 + (size_t)node * DIM + d);
    *(float2*)dst = cur;
}

// ---------------- gather pos/neg outputs from type-1 table ----------------
__global__ __launch_bounds__(256) void gather_kernel(
    const int* __restrict__ pos_ids, const int* __restrict__ neg_ids,
    const float* __restrict__ tbl1, float* __restrict__ outp, float* __restrict__ outn)
{
    int i = blockIdx.x * 256 + threadIdx.x;   // over 2 * NB * 32 float4s
    const int half = NB * 32;
    const int* ids; float* dst; int j = i;
    if (i < half) { ids = pos_ids; dst = outp; }
    else          { ids = neg_ids; dst = outn; j -= half; }
    int b = j >> 5, c = j & 31;
    int id = ids[b];
    ((floatx4*)dst)[j] = ((const floatx4*)tbl1)[(size_t)id * 32 + c];
}

extern "C" void kernel_launch(void* const* d_in, const int* in_sizes, int n_in,
                              void* d_out, int out_size, void* d_ws, size_t ws_size,
                              hipStream_t stream)
{
    const int* c_ids   = (const int*)d_in[0];
    const int* pos_ids = (const int*)d_in[1];
    const int* neg_ids = (const int*)d_in[2];
    const int* nb00 = (const int*)d_in[3];
    const int* nb01 = (const int*)d_in[4];
    const int* nb02 = (const int*)d_in[5];
    const int* nb10 = (const int*)d_in[6];
    const int* nb11 = (const int*)d_in[7];
    const int* nb12 = (const int*)d_in[8];
    const float* emb0 = (const float*)d_in[12];
    const float* emb1 = (const float*)d_in[13];
    const float* emb2 = (const float*)d_in[14];
    const float* rWih = (const float*)d_in[15];
    const float* rWhh = (const float*)d_in[16];
    const float* rbih = (const float*)d_in[17];
    const float* rbhh = (const float*)d_in[18];
    const float* attW = (const float*)d_in[19];

    char* ws = (char*)d_ws;
    _Float16* he0  = (_Float16*)(ws + OFF_HE0);
    _Float16* he1  = (_Float16*)(ws + OFF_HE1);
    _Float16* he2  = (_Float16*)(ws + OFF_HE2);
    _Float16* hwih = (_Float16*)(ws + OFF_WIH);
    _Float16* hwhh = (_Float16*)(ws + OFF_WHH);
    float*    agg0 = (float*)(ws + OFF_AGG0);
    float*    agg1 = (float*)(ws + OFF_AGG1);
    float*    tbl1 = (float*)(ws + OFF_TBL1);

    float* out  = (float*)d_out;
    float* outc = out;
    float* outp = out + (size_t)NB * DIM;
    float* outn = out + (size_t)2 * NB * DIM;

    // 1) fp16 conversion of embeddings + weights
    {
        int total4 = (CN0 + CN1 + CN2) * DIM / 4 + 2 * (2 * 3 * DIM * DIM / 4);
        int blocks = (total4 + 255) / 256;
        prep_kernel<<<blocks, 256, 0, stream>>>(emb0, emb1, emb2, rWih, rWhh,
                                                he0, he1, he2, hwih, hwhh);
    }
    // 2) RNN-mean aggregations: c batch (4096 nodes) + full type-1 table (2048)
    {
        dim3 grid(NB / GMT + T1PAD / GMT, 6);
        rnn_kernel<<<grid, 256, 0, stream>>>(c_ids, nb00, nb01, nb02, nb10, nb11, nb12,
                                             he0, he1, he2, hwih, hwhh, rbih, rbhh,
                                             agg0, agg1);
    }
    // 3) attention combine
    {
        int blocks = NB / 4 + T1PAD / 4;
        att_kernel<<<blocks, 256, 0, stream>>>(c_ids, emb0, emb1, attW, agg0, agg1,
                                               outc, tbl1);
    }
    // 4) gather pos/neg outputs
    {
        int blocks = 2 * NB * 32 / 256;
        gather_kernel<<<blocks, 256, 0, stream>>>(pos_ids, neg_ids, tbl1, outp, outn);
    }
}